// Round 8
// baseline (405.031 us; speedup 1.0000x reference)
//
#include <hip/hip_runtime.h>

typedef __bf16 bf16x8 __attribute__((ext_vector_type(8)));
typedef float f32x4 __attribute__((ext_vector_type(4)));
typedef unsigned short u16;
typedef unsigned int u32;
typedef unsigned long long u64;

__device__ __forceinline__ u16 f2b(float f) {
  return __builtin_bit_cast(u16, (__bf16)f);
}
__device__ __forceinline__ float b2f_lo(u32 pk) {
  return __builtin_bit_cast(float, pk << 16);
}
__device__ __forceinline__ float b2f_hi(u32 pk) {
  return __builtin_bit_cast(float, pk & 0xffff0000u);
}
__device__ __forceinline__ float leaky(float x) { return x > 0.f ? x : 0.1f * x; }
__device__ __forceinline__ f32x4 mfma16(bf16x8 a, bf16x8 b, f32x4 c) {
  return __builtin_amdgcn_mfma_f32_16x16x32_bf16(a, b, c, 0, 0, 0);
}

// LDS row paddings: 64->72, 128->136 u16 (stride%32 dwords = 4 -> 2-way, free)
#define P64 72
#define P128 136
// fixed-stride CSR record, 128B (2 cache lines), 32 ints:
//   int[0]=cnt  int[1]=pspill(float, spill-only possum)
//   int[2+j] = slot j = (src<<12) | fix12(bitpos)   (src < 2^20, 12-bit pos)
#define CAP 16
#define RSTRIDE 32  // ints

// roles in k_mid: [0,PREPB) tail-weight prep, [PREPB,PREPB+SBLK) scatter,
// [PREPB+SBLK, +PBLK) pre. Roles touch disjoint data; prep-role outputs are
// consumed only by LATER kernels (stream order guarantees visibility).
#define PREPB 32
#define SBLK 256
#define PBLK 256

// ======= k_zero2: zero record headers + spillcnt + mbits ballot =============
__global__ __launch_bounds__(256) void k_zero2(int* rec, int* spillcnt,
                                               const int* is_module, u32* mbits,
                                               int N) {
  int n = blockIdx.x * 256 + threadIdx.x;
  int lane = threadIdx.x & 63;
  bool v = (n < N) && (is_module[n] == 1);
  u64 b = __ballot(v);
  if (n < N) {
    rec[(size_t)n * RSTRIDE] = 0;
    rec[(size_t)n * RSTRIDE + 1] = 0;
    if (lane == 0) mbits[n >> 5] = (u32)b;
    if (lane == 32) mbits[n >> 5] = (u32)(b >> 32);
  }
  if (n == 0) *spillcnt = 0;
}

// ====== k_mid (fused): prep-tail || scatter || pre ==========================
// scatter role: verbatim R3 ILP-batched body. pre role: verbatim R3 compute,
// weights now folded into LDS locally (same formulas as old k_prep).
// prep-tail role: verbatim k_prep segments for wt2m/wt2g/wt_oh/gt/bp/w_pos.
__global__ __launch_bounds__(512) void k_mid(
    const int* src_m, const int* dst_m, const int* src_g, const int* dst_g,
    const u32* mbits, const float* bitpos, int* rec, u64* spill, int* spillcnt,
    int E,
    const float* pf, const float* feat, const float* pi_w1, const float* pi_b1,
    const float* pi_w2, const float* pi_b2,
    const float* nm_w1, const float* ng_w1, const float* nm_b1, const float* ng_b1,
    const float* nm_w2, const float* ng_w2, const float* o_w1, const float* o_b1,
    const float* g_w2, const float* g_b2,
    u16* y0, u16* f1,
    u16* wt2m, u16* wt2g, u16* wt_oh, u16* gt, float* bp, float* w_pos, int N) {
  __shared__ __align__(16) u16 wyc[2][64 * P64];
  __shared__ __align__(16) u16 wf[2][64 * P64];
  __shared__ __align__(16) u16 tbuf[8][16 * P64];
  __shared__ float bias_l[128];

  if (blockIdx.x < PREPB) {
    // -------- prep-tail role: weights for k_gather/k_tail (to global) -------
    // items: wt2m 9216 | wt2g 9216 | wt_oh 17408 | gt 9216 | bp 128 | w_pos 64
    const int TOTAL = 9216 + 9216 + 17408 + 9216 + 128 + 64;
    for (int it = blockIdx.x * 512 + threadIdx.x; it < TOTAL; it += PREPB * 512) {
      int i = it;
      if (i < 9216) {
        int n = i / P64, k = i % P64;
        wt2m[i] = f2b(k < 64 ? nm_w2[k * 128 + n] : 0.f);
        continue;
      }
      i -= 9216;
      if (i < 9216) {
        int n = i / P64, k = i % P64;
        wt2g[i] = f2b(k < 64 ? ng_w2[k * 128 + n] : 0.f);
        continue;
      }
      i -= 9216;
      if (i < 17408) {
        int n = i / P128, k = i % P128;
        wt_oh[i] = f2b(k < 128 ? o_w1[k * 128 + n] : 0.f);
        continue;
      }
      i -= 17408;
      if (i < 9216) {
        int n = i / P64, k = i % P64;
        float v = 0.f;
        if (k < 64)
          for (int t = 0; t < 128; t++) v += g_w2[k * 128 + t] * o_w1[(128 + t) * 128 + n];
        gt[i] = f2b(v);
        continue;
      }
      i -= 9216;
      if (i < 128) {
        float s = o_b1[i];
        for (int t = 0; t < 128; t++) s += g_b2[t] * o_w1[(128 + t) * 128 + i];
        bp[i] = s;
        continue;
      }
      i -= 128;
      w_pos[i] = nm_w1[128 * 64 + i];
    }
    return;
  }

  if (blockIdx.x < PREPB + SBLK) {
    // ---------------- scatter role (ILP-batched, verbatim R3) ---------------
    int tid = (blockIdx.x - PREPB) * 512 + threadIdx.x;
    const int STR = SBLK * 512;
    for (int v0 = tid; v0 < E; v0 += STR * 4) {
      int dd[8], ss[8];
      float bb[8];
      bool el[8];
#pragma unroll
      for (int k = 0; k < 4; k++) {
        int vt = v0 + k * STR;
        bool vv = vt < E;
#pragma unroll
        for (int j = 0; j < 2; j++) {
          int x = k * 2 + j;
          el[x] = false;
          dd[x] = 0; ss[x] = 0; bb[x] = 0.f;
          if (vv) {
            int e = vt * 2 + j;
            int d = (e < E) ? dst_m[e] : dst_g[e - E];
            dd[x] = d;
            bool bit = (mbits[d >> 5] >> (d & 31)) & 1;
            el[x] = (e < E) ? bit : !bit;
            if (el[x]) {
              if (e < E) { ss[x] = src_m[e]; bb[x] = bitpos[e]; }
              else ss[x] = src_g[e - E];
            }
          }
        }
      }
      int cc[8];
#pragma unroll
      for (int x = 0; x < 8; x++)
        if (el[x]) cc[x] = atomicAdd(&rec[(size_t)dd[x] * RSTRIDE], 1);
#pragma unroll
      for (int x = 0; x < 8; x++) {
        if (!el[x]) continue;
        int vt = v0 + (x >> 1) * STR;
        int e = vt * 2 + (x & 1);
        int d = dd[x], s = ss[x], c = cc[x];
        if (e < E) {
          if (c < CAP) {
            int bp12 = (int)(bb[x] * 4096.f);
            if (bp12 > 4095) bp12 = 4095;
            rec[(size_t)d * RSTRIDE + 2 + c] = (s << 12) | bp12;
          } else {
            int p = atomicAdd(spillcnt, 1);
            spill[p] = ((u64)(u32)d << 32) | (u32)s;
            atomicAdd((float*)&rec[(size_t)d * RSTRIDE + 1], bb[x]);
          }
        } else {
          if (c < CAP) {
            rec[(size_t)d * RSTRIDE + 2 + c] = s << 12;
          } else {
            int p = atomicAdd(spillcnt, 1);
            spill[p] = ((u64)(u32)d << 32) | (u32)s;
          }
        }
      }
    }
    return;
  }

  // ---------------- pre role: layer1(pi) -> y0 ; f1 ----------------
  // weight folds computed locally into LDS (formulas verbatim from old k_prep)
  int pb = blockIdx.x - PREPB - SBLK;
  for (int i = threadIdx.x; i < 4608; i += 512) {
    int n = i / P64, k = i % P64;
    wf[0][i] = f2b(k < 64 ? nm_w1[(129 + k) * 64 + n] : 0.f);
    wf[1][i] = f2b(k < 64 ? ng_w1[(128 + k) * 64 + n] : 0.f);
  }
  for (int i = threadIdx.x; i < 9216; i += 512) {
    int ty = i / 4608, rem = i % 4608, n = rem / P64, k = rem % P64;
    float v = 0.f;
    if (k < 64) {
      const float* w1 = ty ? ng_w1 : nm_w1;
      for (int t = 0; t < 128; t++) v += pi_w2[k * 128 + t] * w1[t * 64 + n];
    }
    wyc[ty][rem] = f2b(v);
  }
  for (int i = threadIdx.x; i < 128; i += 512) {
    int ty = i >> 6, n = i & 63;
    const float* w1 = ty ? ng_w1 : nm_w1;
    float v = 0.f;
    for (int t = 0; t < 128; t++) v += pi_b2[t] * w1[t * 64 + n];
    bias_l[i] = v;
  }

  int lane = threadIdx.x & 63, wv = threadIdx.x >> 6;
  int lid = lane & 15, q = lane >> 4;

  bf16x8 w1f[4];
#pragma unroll
  for (int nt = 0; nt < 4; nt++) {
    bf16x8 f;
#pragma unroll
    for (int j = 0; j < 8; j++) {
      int k = q * 8 + j;
      f[j] = (__bf16)((k < 4) ? pi_w1[k * 64 + nt * 16 + lid] : 0.f);
    }
    w1f[nt] = f;
  }
  __syncthreads();  // weight LDS ready

  int nbat = (N + 15) >> 4;
  for (int b0 = pb * 8; b0 < nbat; b0 += PBLK * 8) {
    int b = b0 + wv;
    int batch = b < nbat ? b : nbat - 1;
    int id = batch * 16 + lid;
    if (id >= N) id = N - 1;

    // ---- pi layer 1: 4 -> 64, leaky -> tbuf (A-layout transpose)
    bf16x8 a;
#pragma unroll
    for (int j = 0; j < 8; j++)
      a[j] = (__bf16)((q == 0 && j < 4) ? pf[(size_t)id * 4 + j] : 0.f);
    f32x4 z1[4];
#pragma unroll
    for (int nt = 0; nt < 4; nt++) {
      f32x4 c = {0.f, 0.f, 0.f, 0.f};
      z1[nt] = mfma16(a, w1f[nt], c);
    }
    __syncthreads();
#pragma unroll
    for (int nt = 0; nt < 4; nt++) {
      float bb = pi_b1[nt * 16 + lid];
#pragma unroll
      for (int r = 0; r < 4; r++)
        tbuf[wv][(q * 4 + r) * P64 + nt * 16 + lid] = f2b(leaky(z1[nt][r] + bb));
    }
    __syncthreads();
    bf16x8 a20 = *(const bf16x8*)&tbuf[wv][lid * P64 + q * 8];
    bf16x8 a21 = *(const bf16x8*)&tbuf[wv][lid * P64 + 32 + q * 8];

    int idr_[4];
#pragma unroll
    for (int r = 0; r < 4; r++) {
      int ii = batch * 16 + q * 4 + r;
      idr_[r] = ii < N ? ii : N - 1;
    }

    // ---- y0[ty] = a2 @ Wcomb_ty + bias_y_ty (64 -> 64 per type)
#pragma unroll
    for (int ty = 0; ty < 2; ty++) {
#pragma unroll
      for (int nt = 0; nt < 4; nt++) {
        f32x4 c = {0.f, 0.f, 0.f, 0.f};
        c = mfma16(a20, *(const bf16x8*)&wyc[ty][(nt * 16 + lid) * P64 + q * 8], c);
        c = mfma16(a21, *(const bf16x8*)&wyc[ty][(nt * 16 + lid) * P64 + 32 + q * 8], c);
        float by = bias_l[ty * 64 + nt * 16 + lid];
#pragma unroll
        for (int r = 0; r < 4; r++)
          y0[(size_t)idr_[r] * 128 + ty * 64 + nt * 16 + lid] = f2b(c[r] + by);
      }
    }

    // ---- f1 = feat @ W1_feat(own type) + b1(own type)
    bf16x8 af[2];
#pragma unroll
    for (int kt = 0; kt < 2; kt++) {
      const float4* p = (const float4*)(feat + (size_t)id * 64 + kt * 32 + q * 8);
      float4 xa = p[0], xb = p[1];
      bf16x8 f;
      f[0] = (__bf16)xa.x; f[1] = (__bf16)xa.y; f[2] = (__bf16)xa.z; f[3] = (__bf16)xa.w;
      f[4] = (__bf16)xb.x; f[5] = (__bf16)xb.y; f[6] = (__bf16)xb.z; f[7] = (__bf16)xb.w;
      af[kt] = f;
    }
#pragma unroll
    for (int nt = 0; nt < 4; nt++) {
      f32x4 cm = {0.f, 0.f, 0.f, 0.f}, cg = {0.f, 0.f, 0.f, 0.f};
#pragma unroll
      for (int kt = 0; kt < 2; kt++) {
        cm = mfma16(af[kt], *(const bf16x8*)&wf[0][(nt * 16 + lid) * P64 + kt * 32 + q * 8], cm);
        cg = mfma16(af[kt], *(const bf16x8*)&wf[1][(nt * 16 + lid) * P64 + kt * 32 + q * 8], cg);
      }
      float bm = nm_b1[nt * 16 + lid], bg = ng_b1[nt * 16 + lid];
#pragma unroll
      for (int r = 0; r < 4; r++) {
        int idr = idr_[r];
        bool mod = (mbits[idr >> 5] >> (idr & 31)) & 1;
        f1[(size_t)idr * 64 + nt * 16 + lid] = f2b(mod ? cm[r] + bm : cg[r] + bg);
      }
    }
  }
}

// ================= k_gather: mean via packed 4B slots (+spill) -> z1a ========
// (verbatim R7: 4 edges in flight per round via four 16-lane groups)
__global__ __launch_bounds__(256) void k_gather(const u16* y0, const int* rec,
                                                const u64* spill, const int* spillcnt,
                                                const u32* mbits, const u16* f1,
                                                const float* w_pos, u16* z1a, int N) {
  int n = (blockIdx.x * 256 + threadIdx.x) >> 6;
  int lane = threadIdx.x & 63;
  if (n >= N) return;
  bool mod = (mbits[n >> 5] >> (n & 31)) & 1;
  int g = lane >> 4, l16 = lane & 15;
  int rv = (lane < 18) ? rec[(size_t)n * RSTRIDE + lane] : 0;
  int cnt = __shfl(rv, 0);
  float pspill = __builtin_bit_cast(float, __shfl(rv, 1));
  int inl = cnt < CAP ? cnt : CAP;
  float myb = 0.f;
  if (mod && lane >= 2 && lane < 18 && (lane - 2) < inl)
    myb = (float)(rv & 4095) * (1.f / 4096.f);
  const u32* yrow = (const u32*)y0;  // 64 u32 per node row
  int halfo = mod ? 0 : 32;
  float a00 = 0.f, a01 = 0.f, a10 = 0.f, a11 = 0.f;
  for (int j = 0; j < inl; j += 4) {
    int e = j + g;
    if (e < inl) {
      int s = (int)(((u32)__shfl(rv, 2 + e)) >> 12);  // src of slot e
      u64 pk = *(const u64*)(yrow + (size_t)s * 64 + halfo + 2 * l16);
      u32 p0 = (u32)pk, p1 = (u32)(pk >> 32);
      a00 += b2f_lo(p0); a01 += b2f_hi(p0);
      a10 += b2f_lo(p1); a11 += b2f_hi(p1);
    }
  }
  if (cnt > CAP) {  // rare: scan spill list (round-robin edges over 4 groups)
    int sc = *spillcnt;
    int idx = 0;
    for (int base = 0; base < sc; base += 64) {
      int i = base + lane;
      u64 ent = (i < sc) ? spill[i] : 0xffffffffffffffffull;
      bool m = ((int)(ent >> 32) == n);
      u64 bal = __ballot(m);
      int slo = (int)(ent & 0xffffffffu);
      while (bal) {
        int l = __ffsll((long long)bal) - 1;
        bal &= bal - 1;
        int s = __shfl(slo, l);
        if ((idx & 3) == g) {
          u64 pk = *(const u64*)(yrow + (size_t)s * 64 + halfo + 2 * l16);
          u32 p0 = (u32)pk, p1 = (u32)(pk >> 32);
          a00 += b2f_lo(p0); a01 += b2f_hi(p0);
          a10 += b2f_lo(p1); a11 += b2f_hi(p1);
        }
        idx++;
      }
    }
  }
  a00 += __shfl_xor(a00, 16); a00 += __shfl_xor(a00, 32);
  a01 += __shfl_xor(a01, 16); a01 += __shfl_xor(a01, 32);
  a10 += __shfl_xor(a10, 16); a10 += __shfl_xor(a10, 32);
  a11 += __shfl_xor(a11, 16); a11 += __shfl_xor(a11, 32);
#pragma unroll
  for (int off = 1; off < 64; off <<= 1) myb += __shfl_xor(myb, off);
  float psum = pspill + myb;
  float inv = 1.f / (float)(cnt > 1 ? cnt : 1);
  if (lane < 16) {
    u64 fp2 = *(const u64*)(((const u32*)f1) + (size_t)n * 32 + 2 * l16);
    u32 f0 = (u32)fp2, f1v = (u32)(fp2 >> 32);
    float z00 = a00 * inv + b2f_lo(f0);
    float z01 = a01 * inv + b2f_hi(f0);
    float z10 = a10 * inv + b2f_lo(f1v);
    float z11 = a11 * inv + b2f_hi(f1v);
    if (mod) {
      float pm = psum * inv;
      float4 wp = ((const float4*)w_pos)[l16];
      z00 += pm * wp.x; z01 += pm * wp.y;
      z10 += pm * wp.z; z11 += pm * wp.w;
    }
    u32 r0 = (u32)f2b(leaky(z00)) | ((u32)f2b(leaky(z01)) << 16);
    u32 r1 = (u32)f2b(leaky(z10)) | ((u32)f2b(leaky(z11)) << 16);
    *(u64*)(((u32*)z1a) + (size_t)n * 32 + 2 * l16) = ((u64)r1 << 32) | r0;
  }
}

// ====== k_tail (persistent, fused): layer2 + select + relu + readout =========
// (verbatim R3/R7 text, in-loop barriers retained)
__global__ __launch_bounds__(512) void k_tail(const u16* z1a, const u16* wt2m_g,
                                              const u16* wt2g_g, const float* nm_b2,
                                              const float* ng_b2, const u32* mbits,
                                              const int* is_po, const float* level,
                                              const float* g_w1, const float* g_b1,
                                              const u16* wt_oh_g, const u16* gt_g,
                                              const float* bp_g, const float* o_w2,
                                              const float* o_b2, float* out, int N) {
  __shared__ __align__(16) u16 w2[2][128 * P64];
  __shared__ __align__(16) u16 wt_oh[128 * P128];
  __shared__ __align__(16) u16 gt[128 * P64];
  __shared__ __align__(16) u16 tbuf[8][16 * P128];
  for (int i = threadIdx.x; i < 128 * P64 / 2; i += 512) {
    ((u32*)w2[0])[i] = ((const u32*)wt2m_g)[i];
    ((u32*)w2[1])[i] = ((const u32*)wt2g_g)[i];
    ((u32*)gt)[i] = ((const u32*)gt_g)[i];
  }
  for (int i = threadIdx.x; i < 128 * P128 / 2; i += 512)
    ((u32*)wt_oh)[i] = ((const u32*)wt_oh_g)[i];

  int lane = threadIdx.x & 63, wv = threadIdx.x >> 6;
  int lid = lane & 15, q = lane >> 4;
  int nbat = (N + 15) >> 4;

  float gw[2][8], gb[2][8];
#pragma unroll
  for (int kt = 0; kt < 2; kt++)
#pragma unroll
    for (int j = 0; j < 8; j++) {
      int k = kt * 32 + q * 8 + j;
      gw[kt][j] = g_w1[k];
      gb[kt][j] = g_b1[k];
    }
  float w2o[8], bpv[8];
#pragma unroll
  for (int nt = 0; nt < 8; nt++) {
    w2o[nt] = o_w2[nt * 16 + lid];
    bpv[nt] = bp_g[nt * 16 + lid];
  }
  float b2m[8], b2g[8];
#pragma unroll
  for (int nt = 0; nt < 8; nt++) {
    b2m[nt] = nm_b2[nt * 16 + lid];
    b2g[nt] = ng_b2[nt * 16 + lid];
  }
  float ob2 = o_b2[0];
  __syncthreads();  // weight LDS ready

  for (int b0 = blockIdx.x * 8; b0 < nbat; b0 += gridDim.x * 8) {
    int b = b0 + wv;
    int batch = b < nbat ? b : nbat - 1;
    int id = batch * 16 + lid;
    if (id >= N) id = N - 1;

    // ---- phase 1: layer-2 both types, select, relu -> tbuf (C-layout write)
    bf16x8 a0 = *(const bf16x8*)(z1a + (size_t)id * 64 + q * 8);
    bf16x8 a1 = *(const bf16x8*)(z1a + (size_t)id * 64 + 32 + q * 8);
    bool mod_[4], kp_[4];
#pragma unroll
    for (int r = 0; r < 4; r++) {
      int ii = batch * 16 + q * 4 + r;
      if (ii >= N) ii = N - 1;
      mod_[r] = (mbits[ii >> 5] >> (ii & 31)) & 1;
      kp_[r] = (is_po[ii] != 1);
    }
    __syncthreads();  // tbuf free (prev iter's reads done)
#pragma unroll
    for (int nt = 0; nt < 8; nt++) {
      f32x4 cm = {0.f, 0.f, 0.f, 0.f}, cg = {0.f, 0.f, 0.f, 0.f};
      cm = mfma16(a0, *(const bf16x8*)&w2[0][(nt * 16 + lid) * P64 + q * 8], cm);
      cm = mfma16(a1, *(const bf16x8*)&w2[0][(nt * 16 + lid) * P64 + 32 + q * 8], cm);
      cg = mfma16(a0, *(const bf16x8*)&w2[1][(nt * 16 + lid) * P64 + q * 8], cg);
      cg = mfma16(a1, *(const bf16x8*)&w2[1][(nt * 16 + lid) * P64 + 32 + q * 8], cg);
#pragma unroll
      for (int r = 0; r < 4; r++) {
        float v = mod_[r] ? cm[r] + b2m[nt] : cg[r] + b2g[nt];
        if (kp_[r]) v = fmaxf(v, 0.f);
        tbuf[wv][(q * 4 + r) * P128 + nt * 16 + lid] = f2b(v);
      }
    }
    __syncthreads();  // tbuf transpose visible

    // ---- phase 2: readout (h A-frags from tbuf + global branch)
    bf16x8 ah[4];
#pragma unroll
    for (int kt = 0; kt < 4; kt++)
      ah[kt] = *(const bf16x8*)&tbuf[wv][lid * P128 + kt * 32 + q * 8];
    float lv = level[id];
    bf16x8 ag[2];
#pragma unroll
    for (int kt = 0; kt < 2; kt++)
#pragma unroll
      for (int j = 0; j < 8; j++)
        ag[kt][j] = (__bf16)leaky(lv * gw[kt][j] + gb[kt][j]);

    f32x4 accv[8];
#pragma unroll
    for (int nt = 0; nt < 8; nt++) {
      f32x4 c = {0.f, 0.f, 0.f, 0.f};
#pragma unroll
      for (int kt = 0; kt < 4; kt++)
        c = mfma16(ah[kt], *(const bf16x8*)&wt_oh[(nt * 16 + lid) * P128 + kt * 32 + q * 8], c);
#pragma unroll
      for (int kt = 0; kt < 2; kt++)
        c = mfma16(ag[kt], *(const bf16x8*)&gt[(nt * 16 + lid) * P64 + kt * 32 + q * 8], c);
      accv[nt] = c;
    }
    float p[4];
#pragma unroll
    for (int r = 0; r < 4; r++) {
      float s = 0.f;
#pragma unroll
      for (int nt = 0; nt < 8; nt++) s += leaky(accv[nt][r] + bpv[nt]) * w2o[nt];
      p[r] = s;
    }
#pragma unroll
    for (int r = 0; r < 4; r++)
#pragma unroll
      for (int off = 1; off < 16; off <<= 1) p[r] += __shfl_xor(p[r], off, 16);
    if (lid == 0) {
#pragma unroll
      for (int r = 0; r < 4; r++) {
        int idr = batch * 16 + q * 4 + r;
        if (idr >= N) idr = N - 1;
        out[idr] = p[r] + ob2;
      }
    }
  }
}

extern "C" void kernel_launch(void* const* d_in, const int* in_sizes, int n_in,
                              void* d_out, int out_size, void* d_ws, size_t ws_size,
                              hipStream_t stream) {
  const float* feat = (const float*)d_in[0];
  const float* pi_feat = (const float*)d_in[1];
  const float* level = (const float*)d_in[2];
  const float* bitpos = (const float*)d_in[3];
  const int* is_po = (const int*)d_in[4];
  const int* is_module = (const int*)d_in[5];
  const int* src_m = (const int*)d_in[6];
  const int* dst_m = (const int*)d_in[7];
  const int* src_g = (const int*)d_in[8];
  const int* dst_g = (const int*)d_in[9];
  const float* pi_w1 = (const float*)d_in[10];
  const float* pi_b1 = (const float*)d_in[11];
  const float* pi_w2 = (const float*)d_in[12];
  const float* pi_b2 = (const float*)d_in[13];
  const float* nm_w1 = (const float*)d_in[14];
  const float* nm_b1 = (const float*)d_in[15];
  const float* nm_w2 = (const float*)d_in[16];
  const float* nm_b2 = (const float*)d_in[17];
  const float* ng_w1 = (const float*)d_in[18];
  const float* ng_b1 = (const float*)d_in[19];
  const float* ng_w2 = (const float*)d_in[20];
  const float* ng_b2 = (const float*)d_in[21];
  const float* g_w1 = (const float*)d_in[22];
  const float* g_b1 = (const float*)d_in[23];
  const float* g_w2 = (const float*)d_in[24];
  const float* g_b2 = (const float*)d_in[25];
  const float* o_w1 = (const float*)d_in[26];
  const float* o_b1 = (const float*)d_in[27];
  const float* o_w2 = (const float*)d_in[28];
  const float* o_b2 = (const float*)d_in[29];

  int N = in_sizes[0] / 64;
  int E = in_sizes[3];

  char* ws = (char*)d_ws;
  size_t off = 0;
  auto alloc = [&](size_t bytes) {
    char* p = ws + off;
    off += (bytes + 255) & ~(size_t)255;
    return p;
  };
  int* rec = (int*)alloc(((size_t)N * RSTRIDE + 64) * 4);
  int* spillcnt = (int*)alloc(16);
  u64* spill = (u64*)alloc((size_t)2 * E * 8);
  u32* mbits = (u32*)alloc((size_t)((N + 31) / 32) * 4);
  u16* y0 = (u16*)alloc((size_t)N * 128 * 2);
  u16* f1 = (u16*)alloc((size_t)N * 64 * 2);
  u16* z1a = (u16*)alloc((size_t)N * 64 * 2);
  float* w_pos = (float*)alloc(64 * 4);
  u16* wt2m = (u16*)alloc(9216 * 2);
  u16* wt2g = (u16*)alloc(9216 * 2);
  u16* wt_oh = (u16*)alloc(17408 * 2);
  u16* gt = (u16*)alloc(9216 * 2);
  float* bp = (float*)alloc(128 * 4);

  // 0. zero record headers + spillcnt + mbits ballot
  k_zero2<<<(N + 255) / 256, 256, 0, stream>>>(rec, spillcnt, is_module, mbits, N);

  // 1. fused: tail-weight prep || edge scatter || node precompute
  //    (k_prep stage eliminated: pre role folds its weights into LDS locally;
  //     tail/gather weights produced by the 32-block prep role, consumed only
  //     by later kernels -> stream order guarantees visibility)
  k_mid<<<PREPB + SBLK + PBLK, 512, 0, stream>>>(
      src_m, dst_m, src_g, dst_g, mbits, bitpos, rec, spill, spillcnt, E,
      pi_feat, feat, pi_w1, pi_b1, pi_w2, pi_b2,
      nm_w1, ng_w1, nm_b1, ng_b1,
      nm_w2, ng_w2, o_w1, o_b1, g_w2, g_b2,
      y0, f1, wt2m, wt2g, wt_oh, gt, bp, w_pos, N);

  // 2. gather + layer-1 finalize
  k_gather<<<(N * 64 + 255) / 256, 256, 0, stream>>>(
      y0, rec, spill, spillcnt, mbits, f1, w_pos, z1a, N);

  // 3. fused tail: layer-2 + select + relu + readout
  k_tail<<<256, 512, 0, stream>>>(z1a, wt2m, wt2g, nm_b2, ng_b2, mbits, is_po,
                                  level, g_w1, g_b1, wt_oh, gt, bp, o_w2, o_b2,
                                  (float*)d_out, N);
}

// Round 9
// 260.916 us; speedup vs baseline: 1.5523x; 1.5523x over previous
//
#include <hip/hip_runtime.h>

typedef __bf16 bf16x8 __attribute__((ext_vector_type(8)));
typedef float f32x4 __attribute__((ext_vector_type(4)));
typedef unsigned short u16;
typedef unsigned int u32;
typedef unsigned long long u64;

__device__ __forceinline__ u16 f2b(float f) {
  return __builtin_bit_cast(u16, (__bf16)f);
}
__device__ __forceinline__ float b2f_lo(u32 pk) {
  return __builtin_bit_cast(float, pk << 16);
}
__device__ __forceinline__ float b2f_hi(u32 pk) {
  return __builtin_bit_cast(float, pk & 0xffff0000u);
}
__device__ __forceinline__ float leaky(float x) { return x > 0.f ? x : 0.1f * x; }
__device__ __forceinline__ f32x4 mfma16(bf16x8 a, bf16x8 b, f32x4 c) {
  return __builtin_amdgcn_mfma_f32_16x16x32_bf16(a, b, c, 0, 0, 0);
}

// LDS row paddings: 64->72, 128->136 u16 (stride%32 dwords = 4 -> 2-way, free)
#define P64 72
#define P128 136
// fixed-stride CSR record, 128B (2 cache lines), 32 ints:
//   int[0]=cnt  int[1]=pspill(float, spill-only possum)
//   int[2+j] = slot j = (src<<12) | fix12(bitpos)   (src < 2^20, 12-bit pos)
#define CAP 16
#define RSTRIDE 32  // ints

// roles in k_mid: [0,PREPB) tail-weight prep, [PREPB,PREPB+SBLK) scatter,
// [PREPB+SBLK,+PBLK) pre. 512 blocks total -> all co-resident at 2 blk/CU.
// prep-role outputs consumed only by LATER kernels (stream order -> safe).
#define PREPB 32
#define SBLK 256
#define PBLK 224

// ====== k_init: pre-weight folds (ONCE, grid-wide) + ballot + zeroing =======
// segments: wt_yc 9216 | bias_y 128 | wt_f1m 4608 | wt_f1g 4608 | ballot+zero
// boundary 18560 % 64 == 0 -> ballot waves stay segment-pure.
__global__ __launch_bounds__(256) void k_init(
    const float* nm_w1, const float* ng_w1, const float* pi_w2, const float* pi_b2,
    const int* is_module,
    u16* wt_yc, float* bias_y, u16* wt_f1m, u16* wt_f1g,
    int* rec, int* spillcnt, u32* mbits, int N) {
  int i = blockIdx.x * 256 + threadIdx.x;
  if (i < 9216) {
    int ty = i / 4608, rem = i % 4608, n = rem / P64, k = rem % P64;
    float v = 0.f;
    if (k < 64) {
      const float* w1 = ty ? ng_w1 : nm_w1;
      for (int t = 0; t < 128; t++) v += pi_w2[k * 128 + t] * w1[t * 64 + n];
    }
    wt_yc[i] = f2b(v);
    return;
  }
  i -= 9216;
  if (i < 128) {
    int ty = i >> 6, n = i & 63;
    const float* w1 = ty ? ng_w1 : nm_w1;
    float v = 0.f;
    for (int t = 0; t < 128; t++) v += pi_b2[t] * w1[t * 64 + n];
    bias_y[i] = v;
    return;
  }
  i -= 128;
  if (i < 4608) {
    int n = i / P64, k = i % P64;
    wt_f1m[i] = f2b(k < 64 ? nm_w1[(129 + k) * 64 + n] : 0.f);
    return;
  }
  i -= 4608;
  if (i < 4608) {
    int n = i / P64, k = i % P64;
    wt_f1g[i] = f2b(k < 64 ? ng_w1[(128 + k) * 64 + n] : 0.f);
    return;
  }
  i -= 4608;
  // ballot + record-header zero segment (wave-aligned: 18560 % 64 == 0)
  {
    int n = i;
    int lane = threadIdx.x & 63;
    bool v = (n < N) && (is_module[n] == 1);
    u64 b = __ballot(v);
    if (n < N) {
      rec[(size_t)n * RSTRIDE] = 0;
      rec[(size_t)n * RSTRIDE + 1] = 0;
      if (lane == 0) mbits[n >> 5] = (u32)b;
      if (lane == 32) mbits[n >> 5] = (u32)(b >> 32);
    }
    if (n == 0) *spillcnt = 0;
  }
}

// ====== k_mid (fused): prep-tail || scatter || pre ==========================
// scatter: verbatim R3/R7 ILP-batched body. pre: verbatim R7 (weights loaded
// from global, produced by k_init). prep-tail: verbatim old k_prep segments.
__global__ __launch_bounds__(512) void k_mid(
    const int* src_m, const int* dst_m, const int* src_g, const int* dst_g,
    const u32* mbits, const float* bitpos, int* rec, u64* spill, int* spillcnt,
    int E,
    const float* pf, const float* feat, const float* pi_w1, const float* pi_b1,
    const u16* wt_yc_g, const float* bias_y, const u16* wt_f1m_g, const u16* wt_f1g_g,
    const float* nm_b1, const float* ng_b1, u16* y0, u16* f1,
    const float* nm_w1, const float* nm_w2, const float* ng_w2,
    const float* o_w1, const float* o_b1, const float* g_w2, const float* g_b2,
    u16* wt2m, u16* wt2g, u16* wt_oh, u16* gt, float* bp, float* w_pos, int N) {
  __shared__ __align__(16) u16 wyc[2][64 * P64];
  __shared__ __align__(16) u16 wf[2][64 * P64];
  __shared__ __align__(16) u16 tbuf[8][16 * P64];

  if (blockIdx.x < PREPB) {
    // -------- prep-tail role: weights for k_gather/k_tail (to global) -------
    const int TOTAL = 9216 + 9216 + 17408 + 9216 + 128 + 64;
    for (int it = blockIdx.x * 512 + threadIdx.x; it < TOTAL; it += PREPB * 512) {
      int i = it;
      if (i < 9216) {
        int n = i / P64, k = i % P64;
        wt2m[i] = f2b(k < 64 ? nm_w2[k * 128 + n] : 0.f);
        continue;
      }
      i -= 9216;
      if (i < 9216) {
        int n = i / P64, k = i % P64;
        wt2g[i] = f2b(k < 64 ? ng_w2[k * 128 + n] : 0.f);
        continue;
      }
      i -= 9216;
      if (i < 17408) {
        int n = i / P128, k = i % P128;
        wt_oh[i] = f2b(k < 128 ? o_w1[k * 128 + n] : 0.f);
        continue;
      }
      i -= 17408;
      if (i < 9216) {
        int n = i / P64, k = i % P64;
        float v = 0.f;
        if (k < 64)
          for (int t = 0; t < 128; t++) v += g_w2[k * 128 + t] * o_w1[(128 + t) * 128 + n];
        gt[i] = f2b(v);
        continue;
      }
      i -= 9216;
      if (i < 128) {
        float s = o_b1[i];
        for (int t = 0; t < 128; t++) s += g_b2[t] * o_w1[(128 + t) * 128 + i];
        bp[i] = s;
        continue;
      }
      i -= 128;
      w_pos[i] = nm_w1[128 * 64 + i];
    }
    return;
  }

  if (blockIdx.x < PREPB + SBLK) {
    // ---------------- scatter role (ILP-batched, verbatim R3) ---------------
    int tid = (blockIdx.x - PREPB) * 512 + threadIdx.x;
    const int STR = SBLK * 512;
    for (int v0 = tid; v0 < E; v0 += STR * 4) {
      int dd[8], ss[8];
      float bb[8];
      bool el[8];
#pragma unroll
      for (int k = 0; k < 4; k++) {
        int vt = v0 + k * STR;
        bool vv = vt < E;
#pragma unroll
        for (int j = 0; j < 2; j++) {
          int x = k * 2 + j;
          el[x] = false;
          dd[x] = 0; ss[x] = 0; bb[x] = 0.f;
          if (vv) {
            int e = vt * 2 + j;
            int d = (e < E) ? dst_m[e] : dst_g[e - E];
            dd[x] = d;
            bool bit = (mbits[d >> 5] >> (d & 31)) & 1;
            el[x] = (e < E) ? bit : !bit;
            if (el[x]) {
              if (e < E) { ss[x] = src_m[e]; bb[x] = bitpos[e]; }
              else ss[x] = src_g[e - E];
            }
          }
        }
      }
      int cc[8];
#pragma unroll
      for (int x = 0; x < 8; x++)
        if (el[x]) cc[x] = atomicAdd(&rec[(size_t)dd[x] * RSTRIDE], 1);
#pragma unroll
      for (int x = 0; x < 8; x++) {
        if (!el[x]) continue;
        int vt = v0 + (x >> 1) * STR;
        int e = vt * 2 + (x & 1);
        int d = dd[x], s = ss[x], c = cc[x];
        if (e < E) {
          if (c < CAP) {
            int bp12 = (int)(bb[x] * 4096.f);
            if (bp12 > 4095) bp12 = 4095;
            rec[(size_t)d * RSTRIDE + 2 + c] = (s << 12) | bp12;
          } else {
            int p = atomicAdd(spillcnt, 1);
            spill[p] = ((u64)(u32)d << 32) | (u32)s;
            atomicAdd((float*)&rec[(size_t)d * RSTRIDE + 1], bb[x]);
          }
        } else {
          if (c < CAP) {
            rec[(size_t)d * RSTRIDE + 2 + c] = s << 12;
          } else {
            int p = atomicAdd(spillcnt, 1);
            spill[p] = ((u64)(u32)d << 32) | (u32)s;
          }
        }
      }
    }
    return;
  }

  // ---------------- pre role: layer1(pi) -> y0 ; f1 (verbatim R7) ----------
  int pb = blockIdx.x - PREPB - SBLK;
  for (int i = threadIdx.x; i < 2304; i += 512) {
    ((u32*)wyc[0])[i] = ((const u32*)wt_yc_g)[i];
    ((u32*)wyc[1])[i] = ((const u32*)wt_yc_g)[2304 + i];
    ((u32*)wf[0])[i] = ((const u32*)wt_f1m_g)[i];
    ((u32*)wf[1])[i] = ((const u32*)wt_f1g_g)[i];
  }

  int lane = threadIdx.x & 63, wv = threadIdx.x >> 6;
  int lid = lane & 15, q = lane >> 4;

  bf16x8 w1f[4];
#pragma unroll
  for (int nt = 0; nt < 4; nt++) {
    bf16x8 f;
#pragma unroll
    for (int j = 0; j < 8; j++) {
      int k = q * 8 + j;
      f[j] = (__bf16)((k < 4) ? pi_w1[k * 64 + nt * 16 + lid] : 0.f);
    }
    w1f[nt] = f;
  }
  __syncthreads();  // weight LDS ready

  int nbat = (N + 15) >> 4;
  for (int b0 = pb * 8; b0 < nbat; b0 += PBLK * 8) {
    int b = b0 + wv;
    int batch = b < nbat ? b : nbat - 1;
    int id = batch * 16 + lid;
    if (id >= N) id = N - 1;

    // ---- pi layer 1: 4 -> 64, leaky -> tbuf (A-layout transpose)
    bf16x8 a;
#pragma unroll
    for (int j = 0; j < 8; j++)
      a[j] = (__bf16)((q == 0 && j < 4) ? pf[(size_t)id * 4 + j] : 0.f);
    f32x4 z1[4];
#pragma unroll
    for (int nt = 0; nt < 4; nt++) {
      f32x4 c = {0.f, 0.f, 0.f, 0.f};
      z1[nt] = mfma16(a, w1f[nt], c);
    }
    __syncthreads();
#pragma unroll
    for (int nt = 0; nt < 4; nt++) {
      float bb = pi_b1[nt * 16 + lid];
#pragma unroll
      for (int r = 0; r < 4; r++)
        tbuf[wv][(q * 4 + r) * P64 + nt * 16 + lid] = f2b(leaky(z1[nt][r] + bb));
    }
    __syncthreads();
    bf16x8 a20 = *(const bf16x8*)&tbuf[wv][lid * P64 + q * 8];
    bf16x8 a21 = *(const bf16x8*)&tbuf[wv][lid * P64 + 32 + q * 8];

    int idr_[4];
#pragma unroll
    for (int r = 0; r < 4; r++) {
      int ii = batch * 16 + q * 4 + r;
      idr_[r] = ii < N ? ii : N - 1;
    }

    // ---- y0[ty] = a2 @ Wcomb_ty + bias_y_ty (64 -> 64 per type)
#pragma unroll
    for (int ty = 0; ty < 2; ty++) {
#pragma unroll
      for (int nt = 0; nt < 4; nt++) {
        f32x4 c = {0.f, 0.f, 0.f, 0.f};
        c = mfma16(a20, *(const bf16x8*)&wyc[ty][(nt * 16 + lid) * P64 + q * 8], c);
        c = mfma16(a21, *(const bf16x8*)&wyc[ty][(nt * 16 + lid) * P64 + 32 + q * 8], c);
        float by = bias_y[ty * 64 + nt * 16 + lid];
#pragma unroll
        for (int r = 0; r < 4; r++)
          y0[(size_t)idr_[r] * 128 + ty * 64 + nt * 16 + lid] = f2b(c[r] + by);
      }
    }

    // ---- f1 = feat @ W1_feat(own type) + b1(own type)
    bf16x8 af[2];
#pragma unroll
    for (int kt = 0; kt < 2; kt++) {
      const float4* p = (const float4*)(feat + (size_t)id * 64 + kt * 32 + q * 8);
      float4 xa = p[0], xb = p[1];
      bf16x8 f;
      f[0] = (__bf16)xa.x; f[1] = (__bf16)xa.y; f[2] = (__bf16)xa.z; f[3] = (__bf16)xa.w;
      f[4] = (__bf16)xb.x; f[5] = (__bf16)xb.y; f[6] = (__bf16)xb.z; f[7] = (__bf16)xb.w;
      af[kt] = f;
    }
#pragma unroll
    for (int nt = 0; nt < 4; nt++) {
      f32x4 cm = {0.f, 0.f, 0.f, 0.f}, cg = {0.f, 0.f, 0.f, 0.f};
#pragma unroll
      for (int kt = 0; kt < 2; kt++) {
        cm = mfma16(af[kt], *(const bf16x8*)&wf[0][(nt * 16 + lid) * P64 + kt * 32 + q * 8], cm);
        cg = mfma16(af[kt], *(const bf16x8*)&wf[1][(nt * 16 + lid) * P64 + kt * 32 + q * 8], cg);
      }
      float bm = nm_b1[nt * 16 + lid], bg = ng_b1[nt * 16 + lid];
#pragma unroll
      for (int r = 0; r < 4; r++) {
        int idr = idr_[r];
        bool mod = (mbits[idr >> 5] >> (idr & 31)) & 1;
        f1[(size_t)idr * 64 + nt * 16 + lid] = f2b(mod ? cm[r] + bm : cg[r] + bg);
      }
    }
  }
}

// ================= k_gather: mean via packed 4B slots (+spill) -> z1a ========
// (verbatim R7: 4 edges in flight per round via four 16-lane groups)
__global__ __launch_bounds__(256) void k_gather(const u16* y0, const int* rec,
                                                const u64* spill, const int* spillcnt,
                                                const u32* mbits, const u16* f1,
                                                const float* w_pos, u16* z1a, int N) {
  int n = (blockIdx.x * 256 + threadIdx.x) >> 6;
  int lane = threadIdx.x & 63;
  if (n >= N) return;
  bool mod = (mbits[n >> 5] >> (n & 31)) & 1;
  int g = lane >> 4, l16 = lane & 15;
  int rv = (lane < 18) ? rec[(size_t)n * RSTRIDE + lane] : 0;
  int cnt = __shfl(rv, 0);
  float pspill = __builtin_bit_cast(float, __shfl(rv, 1));
  int inl = cnt < CAP ? cnt : CAP;
  float myb = 0.f;
  if (mod && lane >= 2 && lane < 18 && (lane - 2) < inl)
    myb = (float)(rv & 4095) * (1.f / 4096.f);
  const u32* yrow = (const u32*)y0;  // 64 u32 per node row
  int halfo = mod ? 0 : 32;
  float a00 = 0.f, a01 = 0.f, a10 = 0.f, a11 = 0.f;
  for (int j = 0; j < inl; j += 4) {
    int e = j + g;
    if (e < inl) {
      int s = (int)(((u32)__shfl(rv, 2 + e)) >> 12);  // src of slot e
      u64 pk = *(const u64*)(yrow + (size_t)s * 64 + halfo + 2 * l16);
      u32 p0 = (u32)pk, p1 = (u32)(pk >> 32);
      a00 += b2f_lo(p0); a01 += b2f_hi(p0);
      a10 += b2f_lo(p1); a11 += b2f_hi(p1);
    }
  }
  if (cnt > CAP) {  // rare: scan spill list (round-robin edges over 4 groups)
    int sc = *spillcnt;
    int idx = 0;
    for (int base = 0; base < sc; base += 64) {
      int i = base + lane;
      u64 ent = (i < sc) ? spill[i] : 0xffffffffffffffffull;
      bool m = ((int)(ent >> 32) == n);
      u64 bal = __ballot(m);
      int slo = (int)(ent & 0xffffffffu);
      while (bal) {
        int l = __ffsll((long long)bal) - 1;
        bal &= bal - 1;
        int s = __shfl(slo, l);
        if ((idx & 3) == g) {
          u64 pk = *(const u64*)(yrow + (size_t)s * 64 + halfo + 2 * l16);
          u32 p0 = (u32)pk, p1 = (u32)(pk >> 32);
          a00 += b2f_lo(p0); a01 += b2f_hi(p0);
          a10 += b2f_lo(p1); a11 += b2f_hi(p1);
        }
        idx++;
      }
    }
  }
  a00 += __shfl_xor(a00, 16); a00 += __shfl_xor(a00, 32);
  a01 += __shfl_xor(a01, 16); a01 += __shfl_xor(a01, 32);
  a10 += __shfl_xor(a10, 16); a10 += __shfl_xor(a10, 32);
  a11 += __shfl_xor(a11, 16); a11 += __shfl_xor(a11, 32);
#pragma unroll
  for (int off = 1; off < 64; off <<= 1) myb += __shfl_xor(myb, off);
  float psum = pspill + myb;
  float inv = 1.f / (float)(cnt > 1 ? cnt : 1);
  if (lane < 16) {
    u64 fp2 = *(const u64*)(((const u32*)f1) + (size_t)n * 32 + 2 * l16);
    u32 f0 = (u32)fp2, f1v = (u32)(fp2 >> 32);
    float z00 = a00 * inv + b2f_lo(f0);
    float z01 = a01 * inv + b2f_hi(f0);
    float z10 = a10 * inv + b2f_lo(f1v);
    float z11 = a11 * inv + b2f_hi(f1v);
    if (mod) {
      float pm = psum * inv;
      float4 wp = ((const float4*)w_pos)[l16];
      z00 += pm * wp.x; z01 += pm * wp.y;
      z10 += pm * wp.z; z11 += pm * wp.w;
    }
    u32 r0 = (u32)f2b(leaky(z00)) | ((u32)f2b(leaky(z01)) << 16);
    u32 r1 = (u32)f2b(leaky(z10)) | ((u32)f2b(leaky(z11)) << 16);
    *(u64*)(((u32*)z1a) + (size_t)n * 32 + 2 * l16) = ((u64)r1 << 32) | r0;
  }
}

// ====== k_tail (persistent, fused): layer2 + select + relu + readout =========
// (verbatim R3/R7 text, in-loop barriers retained)
__global__ __launch_bounds__(512) void k_tail(const u16* z1a, const u16* wt2m_g,
                                              const u16* wt2g_g, const float* nm_b2,
                                              const float* ng_b2, const u32* mbits,
                                              const int* is_po, const float* level,
                                              const float* g_w1, const float* g_b1,
                                              const u16* wt_oh_g, const u16* gt_g,
                                              const float* bp_g, const float* o_w2,
                                              const float* o_b2, float* out, int N) {
  __shared__ __align__(16) u16 w2[2][128 * P64];
  __shared__ __align__(16) u16 wt_oh[128 * P128];
  __shared__ __align__(16) u16 gt[128 * P64];
  __shared__ __align__(16) u16 tbuf[8][16 * P128];
  for (int i = threadIdx.x; i < 128 * P64 / 2; i += 512) {
    ((u32*)w2[0])[i] = ((const u32*)wt2m_g)[i];
    ((u32*)w2[1])[i] = ((const u32*)wt2g_g)[i];
    ((u32*)gt)[i] = ((const u32*)gt_g)[i];
  }
  for (int i = threadIdx.x; i < 128 * P128 / 2; i += 512)
    ((u32*)wt_oh)[i] = ((const u32*)wt_oh_g)[i];

  int lane = threadIdx.x & 63, wv = threadIdx.x >> 6;
  int lid = lane & 15, q = lane >> 4;
  int nbat = (N + 15) >> 4;

  float gw[2][8], gb[2][8];
#pragma unroll
  for (int kt = 0; kt < 2; kt++)
#pragma unroll
    for (int j = 0; j < 8; j++) {
      int k = kt * 32 + q * 8 + j;
      gw[kt][j] = g_w1[k];
      gb[kt][j] = g_b1[k];
    }
  float w2o[8], bpv[8];
#pragma unroll
  for (int nt = 0; nt < 8; nt++) {
    w2o[nt] = o_w2[nt * 16 + lid];
    bpv[nt] = bp_g[nt * 16 + lid];
  }
  float b2m[8], b2g[8];
#pragma unroll
  for (int nt = 0; nt < 8; nt++) {
    b2m[nt] = nm_b2[nt * 16 + lid];
    b2g[nt] = ng_b2[nt * 16 + lid];
  }
  float ob2 = o_b2[0];
  __syncthreads();  // weight LDS ready

  for (int b0 = blockIdx.x * 8; b0 < nbat; b0 += gridDim.x * 8) {
    int b = b0 + wv;
    int batch = b < nbat ? b : nbat - 1;
    int id = batch * 16 + lid;
    if (id >= N) id = N - 1;

    // ---- phase 1: layer-2 both types, select, relu -> tbuf (C-layout write)
    bf16x8 a0 = *(const bf16x8*)(z1a + (size_t)id * 64 + q * 8);
    bf16x8 a1 = *(const bf16x8*)(z1a + (size_t)id * 64 + 32 + q * 8);
    bool mod_[4], kp_[4];
#pragma unroll
    for (int r = 0; r < 4; r++) {
      int ii = batch * 16 + q * 4 + r;
      if (ii >= N) ii = N - 1;
      mod_[r] = (mbits[ii >> 5] >> (ii & 31)) & 1;
      kp_[r] = (is_po[ii] != 1);
    }
    __syncthreads();  // tbuf free (prev iter's reads done)
#pragma unroll
    for (int nt = 0; nt < 8; nt++) {
      f32x4 cm = {0.f, 0.f, 0.f, 0.f}, cg = {0.f, 0.f, 0.f, 0.f};
      cm = mfma16(a0, *(const bf16x8*)&w2[0][(nt * 16 + lid) * P64 + q * 8], cm);
      cm = mfma16(a1, *(const bf16x8*)&w2[0][(nt * 16 + lid) * P64 + 32 + q * 8], cm);
      cg = mfma16(a0, *(const bf16x8*)&w2[1][(nt * 16 + lid) * P64 + q * 8], cg);
      cg = mfma16(a1, *(const bf16x8*)&w2[1][(nt * 16 + lid) * P64 + 32 + q * 8], cg);
#pragma unroll
      for (int r = 0; r < 4; r++) {
        float v = mod_[r] ? cm[r] + b2m[nt] : cg[r] + b2g[nt];
        if (kp_[r]) v = fmaxf(v, 0.f);
        tbuf[wv][(q * 4 + r) * P128 + nt * 16 + lid] = f2b(v);
      }
    }
    __syncthreads();  // tbuf transpose visible

    // ---- phase 2: readout (h A-frags from tbuf + global branch)
    bf16x8 ah[4];
#pragma unroll
    for (int kt = 0; kt < 4; kt++)
      ah[kt] = *(const bf16x8*)&tbuf[wv][lid * P128 + kt * 32 + q * 8];
    float lv = level[id];
    bf16x8 ag[2];
#pragma unroll
    for (int kt = 0; kt < 2; kt++)
#pragma unroll
      for (int j = 0; j < 8; j++)
        ag[kt][j] = (__bf16)leaky(lv * gw[kt][j] + gb[kt][j]);

    f32x4 accv[8];
#pragma unroll
    for (int nt = 0; nt < 8; nt++) {
      f32x4 c = {0.f, 0.f, 0.f, 0.f};
#pragma unroll
      for (int kt = 0; kt < 4; kt++)
        c = mfma16(ah[kt], *(const bf16x8*)&wt_oh[(nt * 16 + lid) * P128 + kt * 32 + q * 8], c);
#pragma unroll
      for (int kt = 0; kt < 2; kt++)
        c = mfma16(ag[kt], *(const bf16x8*)&gt[(nt * 16 + lid) * P64 + kt * 32 + q * 8], c);
      accv[nt] = c;
    }
    float p[4];
#pragma unroll
    for (int r = 0; r < 4; r++) {
      float s = 0.f;
#pragma unroll
      for (int nt = 0; nt < 8; nt++) s += leaky(accv[nt][r] + bpv[nt]) * w2o[nt];
      p[r] = s;
    }
#pragma unroll
    for (int r = 0; r < 4; r++)
#pragma unroll
      for (int off = 1; off < 16; off <<= 1) p[r] += __shfl_xor(p[r], off, 16);
    if (lid == 0) {
#pragma unroll
      for (int r = 0; r < 4; r++) {
        int idr = batch * 16 + q * 4 + r;
        if (idr >= N) idr = N - 1;
        out[idr] = p[r] + ob2;
      }
    }
  }
}

extern "C" void kernel_launch(void* const* d_in, const int* in_sizes, int n_in,
                              void* d_out, int out_size, void* d_ws, size_t ws_size,
                              hipStream_t stream) {
  const float* feat = (const float*)d_in[0];
  const float* pi_feat = (const float*)d_in[1];
  const float* level = (const float*)d_in[2];
  const float* bitpos = (const float*)d_in[3];
  const int* is_po = (const int*)d_in[4];
  const int* is_module = (const int*)d_in[5];
  const int* src_m = (const int*)d_in[6];
  const int* dst_m = (const int*)d_in[7];
  const int* src_g = (const int*)d_in[8];
  const int* dst_g = (const int*)d_in[9];
  const float* pi_w1 = (const float*)d_in[10];
  const float* pi_b1 = (const float*)d_in[11];
  const float* pi_w2 = (const float*)d_in[12];
  const float* pi_b2 = (const float*)d_in[13];
  const float* nm_w1 = (const float*)d_in[14];
  const float* nm_b1 = (const float*)d_in[15];
  const float* nm_w2 = (const float*)d_in[16];
  const float* nm_b2 = (const float*)d_in[17];
  const float* ng_w1 = (const float*)d_in[18];
  const float* ng_b1 = (const float*)d_in[19];
  const float* ng_w2 = (const float*)d_in[20];
  const float* ng_b2 = (const float*)d_in[21];
  const float* g_w1 = (const float*)d_in[22];
  const float* g_b1 = (const float*)d_in[23];
  const float* g_w2 = (const float*)d_in[24];
  const float* g_b2 = (const float*)d_in[25];
  const float* o_w1 = (const float*)d_in[26];
  const float* o_b1 = (const float*)d_in[27];
  const float* o_w2 = (const float*)d_in[28];
  const float* o_b2 = (const float*)d_in[29];

  int N = in_sizes[0] / 64;
  int E = in_sizes[3];

  char* ws = (char*)d_ws;
  size_t off = 0;
  auto alloc = [&](size_t bytes) {
    char* p = ws + off;
    off += (bytes + 255) & ~(size_t)255;
    return p;
  };
  int* rec = (int*)alloc(((size_t)N * RSTRIDE + 64) * 4);
  int* spillcnt = (int*)alloc(16);
  u64* spill = (u64*)alloc((size_t)2 * E * 8);
  u32* mbits = (u32*)alloc((size_t)((N + 31) / 32) * 4);
  u16* y0 = (u16*)alloc((size_t)N * 128 * 2);
  u16* f1 = (u16*)alloc((size_t)N * 64 * 2);
  u16* z1a = (u16*)alloc((size_t)N * 64 * 2);
  u16* wt_yc = (u16*)alloc(9216 * 2);
  float* bias_y = (float*)alloc(128 * 4);
  u16* wt_f1m = (u16*)alloc(4608 * 2);
  u16* wt_f1g = (u16*)alloc(4608 * 2);
  float* w_pos = (float*)alloc(64 * 4);
  u16* wt2m = (u16*)alloc(9216 * 2);
  u16* wt2g = (u16*)alloc(9216 * 2);
  u16* wt_oh = (u16*)alloc(17408 * 2);
  u16* gt = (u16*)alloc(9216 * 2);
  float* bp = (float*)alloc(128 * 4);

  // 0. init: pre-weight folds (once) + mbits ballot + record zero + spillcnt
  int init_items = 18560 + ((N + 63) & ~63);
  k_init<<<(init_items + 255) / 256, 256, 0, stream>>>(
      nm_w1, ng_w1, pi_w2, pi_b2, is_module,
      wt_yc, bias_y, wt_f1m, wt_f1g, rec, spillcnt, mbits, N);

  // 1. fused: tail-weight prep || edge scatter || node precompute
  k_mid<<<PREPB + SBLK + PBLK, 512, 0, stream>>>(
      src_m, dst_m, src_g, dst_g, mbits, bitpos, rec, spill, spillcnt, E,
      pi_feat, feat, pi_w1, pi_b1, wt_yc, bias_y, wt_f1m, wt_f1g,
      nm_b1, ng_b1, y0, f1,
      nm_w1, nm_w2, ng_w2, o_w1, o_b1, g_w2, g_b2,
      wt2m, wt2g, wt_oh, gt, bp, w_pos, N);

  // 2. gather + layer-1 finalize
  k_gather<<<(N * 64 + 255) / 256, 256, 0, stream>>>(
      y0, rec, spill, spillcnt, mbits, f1, w_pos, z1a, N);

  // 3. fused tail: layer-2 + select + relu + readout
  k_tail<<<256, 512, 0, stream>>>(z1a, wt2m, wt2g, nm_b2, ng_b2, mbits, is_po,
                                  level, g_w1, g_b1, wt_oh, gt, bp, o_w2, o_b2,
                                  (float*)d_out, N);
}

// Round 10
// 248.687 us; speedup vs baseline: 1.6287x; 1.0492x over previous
//
#include <hip/hip_runtime.h>

typedef __bf16 bf16x8 __attribute__((ext_vector_type(8)));
typedef float f32x4 __attribute__((ext_vector_type(4)));
typedef unsigned short u16;
typedef unsigned int u32;
typedef unsigned long long u64;

__device__ __forceinline__ u16 f2b(float f) {
  return __builtin_bit_cast(u16, (__bf16)f);
}
__device__ __forceinline__ float b2f_lo(u32 pk) {
  return __builtin_bit_cast(float, pk << 16);
}
__device__ __forceinline__ float b2f_hi(u32 pk) {
  return __builtin_bit_cast(float, pk & 0xffff0000u);
}
__device__ __forceinline__ float leaky(float x) { return x > 0.f ? x : 0.1f * x; }
__device__ __forceinline__ f32x4 mfma16(bf16x8 a, bf16x8 b, f32x4 c) {
  return __builtin_amdgcn_mfma_f32_16x16x32_bf16(a, b, c, 0, 0, 0);
}

// LDS row paddings: 64->72, 128->136 u16 (stride%32 dwords = 4 -> 2-way, free)
#define P64 72
#define P128 136
// fixed-stride CSR record, 128B (2 cache lines), 32 ints:
//   int[0]=cnt  int[1]=pspill(float, spill-only possum)
//   int[2+j] = slot j = (src<<12) | fix12(bitpos)   (src < 2^20, 12-bit pos)
#define CAP 16
#define RSTRIDE 32  // ints

// roles in k_mid: [0,PREPB) tail-weight prep, [PREPB,PREPB+SBLK) scatter,
// [PREPB+SBLK,+PBLK) pre. 512 blocks total -> all co-resident at 2 blk/CU.
#define PREPB 32
#define SBLK 256
#define PBLK 224

// ====== k_init: pre-weight folds (ONCE, grid-wide) + ballot + zeroing =======
__global__ __launch_bounds__(256) void k_init(
    const float* nm_w1, const float* ng_w1, const float* pi_w2, const float* pi_b2,
    const int* is_module,
    u16* wt_yc, float* bias_y, u16* wt_f1m, u16* wt_f1g,
    int* rec, int* spillcnt, u32* mbits, int N) {
  int i = blockIdx.x * 256 + threadIdx.x;
  if (i < 9216) {
    int ty = i / 4608, rem = i % 4608, n = rem / P64, k = rem % P64;
    float v = 0.f;
    if (k < 64) {
      const float* w1 = ty ? ng_w1 : nm_w1;
      for (int t = 0; t < 128; t++) v += pi_w2[k * 128 + t] * w1[t * 64 + n];
    }
    wt_yc[i] = f2b(v);
    return;
  }
  i -= 9216;
  if (i < 128) {
    int ty = i >> 6, n = i & 63;
    const float* w1 = ty ? ng_w1 : nm_w1;
    float v = 0.f;
    for (int t = 0; t < 128; t++) v += pi_b2[t] * w1[t * 64 + n];
    bias_y[i] = v;
    return;
  }
  i -= 128;
  if (i < 4608) {
    int n = i / P64, k = i % P64;
    wt_f1m[i] = f2b(k < 64 ? nm_w1[(129 + k) * 64 + n] : 0.f);
    return;
  }
  i -= 4608;
  if (i < 4608) {
    int n = i / P64, k = i % P64;
    wt_f1g[i] = f2b(k < 64 ? ng_w1[(128 + k) * 64 + n] : 0.f);
    return;
  }
  i -= 4608;
  // ballot + record-header zero segment (wave-aligned: 18560 % 64 == 0)
  {
    int n = i;
    int lane = threadIdx.x & 63;
    bool v = (n < N) && (is_module[n] == 1);
    u64 b = __ballot(v);
    if (n < N) {
      rec[(size_t)n * RSTRIDE] = 0;
      rec[(size_t)n * RSTRIDE + 1] = 0;
      if (lane == 0) mbits[n >> 5] = (u32)b;
      if (lane == 32) mbits[n >> 5] = (u32)(b >> 32);
    }
    if (n == 0) *spillcnt = 0;
  }
}

// ====== k_mid (fused): prep-tail || scatter || pre (verbatim R9) ============
__global__ __launch_bounds__(512) void k_mid(
    const int* src_m, const int* dst_m, const int* src_g, const int* dst_g,
    const u32* mbits, const float* bitpos, int* rec, u64* spill, int* spillcnt,
    int E,
    const float* pf, const float* feat, const float* pi_w1, const float* pi_b1,
    const u16* wt_yc_g, const float* bias_y, const u16* wt_f1m_g, const u16* wt_f1g_g,
    const float* nm_b1, const float* ng_b1, u16* y0, u16* f1,
    const float* nm_w1, const float* nm_w2, const float* ng_w2,
    const float* o_w1, const float* o_b1, const float* g_w2, const float* g_b2,
    u16* wt2m, u16* wt2g, u16* wt_oh, u16* gt, float* bp, float* w_pos, int N) {
  __shared__ __align__(16) u16 wyc[2][64 * P64];
  __shared__ __align__(16) u16 wf[2][64 * P64];
  __shared__ __align__(16) u16 tbuf[8][16 * P64];

  if (blockIdx.x < PREPB) {
    const int TOTAL = 9216 + 9216 + 17408 + 9216 + 128 + 64;
    for (int it = blockIdx.x * 512 + threadIdx.x; it < TOTAL; it += PREPB * 512) {
      int i = it;
      if (i < 9216) {
        int n = i / P64, k = i % P64;
        wt2m[i] = f2b(k < 64 ? nm_w2[k * 128 + n] : 0.f);
        continue;
      }
      i -= 9216;
      if (i < 9216) {
        int n = i / P64, k = i % P64;
        wt2g[i] = f2b(k < 64 ? ng_w2[k * 128 + n] : 0.f);
        continue;
      }
      i -= 9216;
      if (i < 17408) {
        int n = i / P128, k = i % P128;
        wt_oh[i] = f2b(k < 128 ? o_w1[k * 128 + n] : 0.f);
        continue;
      }
      i -= 17408;
      if (i < 9216) {
        int n = i / P64, k = i % P64;
        float v = 0.f;
        if (k < 64)
          for (int t = 0; t < 128; t++) v += g_w2[k * 128 + t] * o_w1[(128 + t) * 128 + n];
        gt[i] = f2b(v);
        continue;
      }
      i -= 9216;
      if (i < 128) {
        float s = o_b1[i];
        for (int t = 0; t < 128; t++) s += g_b2[t] * o_w1[(128 + t) * 128 + i];
        bp[i] = s;
        continue;
      }
      i -= 128;
      w_pos[i] = nm_w1[128 * 64 + i];
    }
    return;
  }

  if (blockIdx.x < PREPB + SBLK) {
    int tid = (blockIdx.x - PREPB) * 512 + threadIdx.x;
    const int STR = SBLK * 512;
    for (int v0 = tid; v0 < E; v0 += STR * 4) {
      int dd[8], ss[8];
      float bb[8];
      bool el[8];
#pragma unroll
      for (int k = 0; k < 4; k++) {
        int vt = v0 + k * STR;
        bool vv = vt < E;
#pragma unroll
        for (int j = 0; j < 2; j++) {
          int x = k * 2 + j;
          el[x] = false;
          dd[x] = 0; ss[x] = 0; bb[x] = 0.f;
          if (vv) {
            int e = vt * 2 + j;
            int d = (e < E) ? dst_m[e] : dst_g[e - E];
            dd[x] = d;
            bool bit = (mbits[d >> 5] >> (d & 31)) & 1;
            el[x] = (e < E) ? bit : !bit;
            if (el[x]) {
              if (e < E) { ss[x] = src_m[e]; bb[x] = bitpos[e]; }
              else ss[x] = src_g[e - E];
            }
          }
        }
      }
      int cc[8];
#pragma unroll
      for (int x = 0; x < 8; x++)
        if (el[x]) cc[x] = atomicAdd(&rec[(size_t)dd[x] * RSTRIDE], 1);
#pragma unroll
      for (int x = 0; x < 8; x++) {
        if (!el[x]) continue;
        int vt = v0 + (x >> 1) * STR;
        int e = vt * 2 + (x & 1);
        int d = dd[x], s = ss[x], c = cc[x];
        if (e < E) {
          if (c < CAP) {
            int bp12 = (int)(bb[x] * 4096.f);
            if (bp12 > 4095) bp12 = 4095;
            rec[(size_t)d * RSTRIDE + 2 + c] = (s << 12) | bp12;
          } else {
            int p = atomicAdd(spillcnt, 1);
            spill[p] = ((u64)(u32)d << 32) | (u32)s;
            atomicAdd((float*)&rec[(size_t)d * RSTRIDE + 1], bb[x]);
          }
        } else {
          if (c < CAP) {
            rec[(size_t)d * RSTRIDE + 2 + c] = s << 12;
          } else {
            int p = atomicAdd(spillcnt, 1);
            spill[p] = ((u64)(u32)d << 32) | (u32)s;
          }
        }
      }
    }
    return;
  }

  // ---------------- pre role: layer1(pi) -> y0 ; f1 (verbatim R7) ----------
  int pb = blockIdx.x - PREPB - SBLK;
  for (int i = threadIdx.x; i < 2304; i += 512) {
    ((u32*)wyc[0])[i] = ((const u32*)wt_yc_g)[i];
    ((u32*)wyc[1])[i] = ((const u32*)wt_yc_g)[2304 + i];
    ((u32*)wf[0])[i] = ((const u32*)wt_f1m_g)[i];
    ((u32*)wf[1])[i] = ((const u32*)wt_f1g_g)[i];
  }

  int lane = threadIdx.x & 63, wv = threadIdx.x >> 6;
  int lid = lane & 15, q = lane >> 4;

  bf16x8 w1f[4];
#pragma unroll
  for (int nt = 0; nt < 4; nt++) {
    bf16x8 f;
#pragma unroll
    for (int j = 0; j < 8; j++) {
      int k = q * 8 + j;
      f[j] = (__bf16)((k < 4) ? pi_w1[k * 64 + nt * 16 + lid] : 0.f);
    }
    w1f[nt] = f;
  }
  __syncthreads();  // weight LDS ready

  int nbat = (N + 15) >> 4;
  for (int b0 = pb * 8; b0 < nbat; b0 += PBLK * 8) {
    int b = b0 + wv;
    int batch = b < nbat ? b : nbat - 1;
    int id = batch * 16 + lid;
    if (id >= N) id = N - 1;

    bf16x8 a;
#pragma unroll
    for (int j = 0; j < 8; j++)
      a[j] = (__bf16)((q == 0 && j < 4) ? pf[(size_t)id * 4 + j] : 0.f);
    f32x4 z1[4];
#pragma unroll
    for (int nt = 0; nt < 4; nt++) {
      f32x4 c = {0.f, 0.f, 0.f, 0.f};
      z1[nt] = mfma16(a, w1f[nt], c);
    }
    __syncthreads();
#pragma unroll
    for (int nt = 0; nt < 4; nt++) {
      float bb = pi_b1[nt * 16 + lid];
#pragma unroll
      for (int r = 0; r < 4; r++)
        tbuf[wv][(q * 4 + r) * P64 + nt * 16 + lid] = f2b(leaky(z1[nt][r] + bb));
    }
    __syncthreads();
    bf16x8 a20 = *(const bf16x8*)&tbuf[wv][lid * P64 + q * 8];
    bf16x8 a21 = *(const bf16x8*)&tbuf[wv][lid * P64 + 32 + q * 8];

    int idr_[4];
#pragma unroll
    for (int r = 0; r < 4; r++) {
      int ii = batch * 16 + q * 4 + r;
      idr_[r] = ii < N ? ii : N - 1;
    }

#pragma unroll
    for (int ty = 0; ty < 2; ty++) {
#pragma unroll
      for (int nt = 0; nt < 4; nt++) {
        f32x4 c = {0.f, 0.f, 0.f, 0.f};
        c = mfma16(a20, *(const bf16x8*)&wyc[ty][(nt * 16 + lid) * P64 + q * 8], c);
        c = mfma16(a21, *(const bf16x8*)&wyc[ty][(nt * 16 + lid) * P64 + 32 + q * 8], c);
        float by = bias_y[ty * 64 + nt * 16 + lid];
#pragma unroll
        for (int r = 0; r < 4; r++)
          y0[(size_t)idr_[r] * 128 + ty * 64 + nt * 16 + lid] = f2b(c[r] + by);
      }
    }

    bf16x8 af[2];
#pragma unroll
    for (int kt = 0; kt < 2; kt++) {
      const float4* p = (const float4*)(feat + (size_t)id * 64 + kt * 32 + q * 8);
      float4 xa = p[0], xb = p[1];
      bf16x8 f;
      f[0] = (__bf16)xa.x; f[1] = (__bf16)xa.y; f[2] = (__bf16)xa.z; f[3] = (__bf16)xa.w;
      f[4] = (__bf16)xb.x; f[5] = (__bf16)xb.y; f[6] = (__bf16)xb.z; f[7] = (__bf16)xb.w;
      af[kt] = f;
    }
#pragma unroll
    for (int nt = 0; nt < 4; nt++) {
      f32x4 cm = {0.f, 0.f, 0.f, 0.f}, cg = {0.f, 0.f, 0.f, 0.f};
#pragma unroll
      for (int kt = 0; kt < 2; kt++) {
        cm = mfma16(af[kt], *(const bf16x8*)&wf[0][(nt * 16 + lid) * P64 + kt * 32 + q * 8], cm);
        cg = mfma16(af[kt], *(const bf16x8*)&wf[1][(nt * 16 + lid) * P64 + kt * 32 + q * 8], cg);
      }
      float bm = nm_b1[nt * 16 + lid], bg = ng_b1[nt * 16 + lid];
#pragma unroll
      for (int r = 0; r < 4; r++) {
        int idr = idr_[r];
        bool mod = (mbits[idr >> 5] >> (idr & 31)) & 1;
        f1[(size_t)idr * 64 + nt * 16 + lid] = f2b(mod ? cm[r] + bm : cg[r] + bg);
      }
    }
  }
}

// ====== k_gt2 (fused gather+tail): 16 nodes/wave gathered IN PARALLEL ========
// gather: 4 lanes per node, each lane owns 8 u32 columns; all row loads
// independent -> ~16x the in-flight bytes of R6's sequential version.
// tail phases verbatim R6 (correctness-verified). zl/tbuf wave-private.
__global__ __launch_bounds__(512) void k_gt2(
    const u16* y0, const int* rec, const u64* spill, const int* spillcnt,
    const u32* mbits, const u16* f1, const float* w_pos,
    const u16* wt2m_g, const u16* wt2g_g, const float* nm_b2, const float* ng_b2,
    const int* is_po, const float* level, const float* g_w1, const float* g_b1,
    const u16* wt_oh_g, const u16* gt_g, const float* bp_g, const float* o_w2,
    const float* o_b2, float* out, int N) {
  __shared__ __align__(16) u16 w2[2][128 * P64];
  __shared__ __align__(16) u16 wt_oh[128 * P128];
  __shared__ __align__(16) u16 gt[128 * P64];
  __shared__ __align__(16) u16 tbuf[8][16 * P128];
  __shared__ __align__(16) u32 zl[8][16][36];  // 36-dword rows
  for (int i = threadIdx.x; i < 128 * P64 / 2; i += 512) {
    ((u32*)w2[0])[i] = ((const u32*)wt2m_g)[i];
    ((u32*)w2[1])[i] = ((const u32*)wt2g_g)[i];
    ((u32*)gt)[i] = ((const u32*)gt_g)[i];
  }
  for (int i = threadIdx.x; i < 128 * P128 / 2; i += 512)
    ((u32*)wt_oh)[i] = ((const u32*)wt_oh_g)[i];

  int lane = threadIdx.x & 63, wv = threadIdx.x >> 6;
  int lid = lane & 15, q = lane >> 4;
  int g4 = lane >> 2, c = lane & 3, base4 = lane & ~3;
  int nbat = (N + 15) >> 4;

  float gw[2][8], gb[2][8];
#pragma unroll
  for (int kt = 0; kt < 2; kt++)
#pragma unroll
    for (int j = 0; j < 8; j++) {
      int k = kt * 32 + q * 8 + j;
      gw[kt][j] = g_w1[k];
      gb[kt][j] = g_b1[k];
    }
  float w2o[8], bpv[8];
#pragma unroll
  for (int nt = 0; nt < 8; nt++) {
    w2o[nt] = o_w2[nt * 16 + lid];
    bpv[nt] = bp_g[nt * 16 + lid];
  }
  float b2m[8], b2g[8];
#pragma unroll
  for (int nt = 0; nt < 8; nt++) {
    b2m[nt] = nm_b2[nt * 16 + lid];
    b2g[nt] = ng_b2[nt * 16 + lid];
  }
  float ob2 = o_b2[0];
  __syncthreads();  // weight LDS ready (only barrier)

  const u32* yrow = (const u32*)y0;  // 64 u32 per node row

  for (int b0 = blockIdx.x * 8; b0 < nbat; b0 += gridDim.x * 8) {
    int b = b0 + wv;
    int batch = b < nbat ? b : nbat - 1;

    // ===== gather phase: 16 nodes in parallel, 4 lanes per node ============
    {
      int n = batch * 16 + g4;
      if (n >= N) n = N - 1;
      bool mod = (mbits[n >> 5] >> (n & 31)) & 1;
      int halfo = mod ? 0 : 32;
      const int* rbase = rec + (size_t)n * RSTRIDE;
      int4 r4 = ((const int4*)rbase)[c];  // lane c: ints [4c,4c+4)
      int e16 = 0, e17 = 0;
      if (c == 1) { e16 = rbase[16]; e17 = rbase[17]; }
      int cnt = __shfl(r4.x, base4);
      float pspill = __builtin_bit_cast(float, __shfl(r4.y, base4));
      int inl = cnt < CAP ? cnt : CAP;
      float myb = 0.f;
      float alo[8], ahi[8];
#pragma unroll
      for (int m = 0; m < 8; m++) { alo[m] = 0.f; ahi[m] = 0.f; }
#pragma unroll
      for (int j = 0; j < 16; j++) {
        int slot;
        if (j < 14) {
          const int own = (j + 2) >> 2, comp = (j + 2) & 3;
          int v = comp == 0 ? r4.x : comp == 1 ? r4.y : comp == 2 ? r4.z : r4.w;
          slot = __shfl(v, base4 + own);
        } else {
          slot = __shfl(j == 14 ? e16 : e17, base4 + 1);
        }
        if (j < inl) {
          if (mod) myb += (float)(slot & 4095) * (1.f / 4096.f);
          int s = (int)(((u32)slot) >> 12);
          const u32* rowp = yrow + (size_t)s * 64 + halfo + c * 8;
          uint4 pa = *(const uint4*)rowp;
          uint4 pb = *(const uint4*)(rowp + 4);
          alo[0] += b2f_lo(pa.x); ahi[0] += b2f_hi(pa.x);
          alo[1] += b2f_lo(pa.y); ahi[1] += b2f_hi(pa.y);
          alo[2] += b2f_lo(pa.z); ahi[2] += b2f_hi(pa.z);
          alo[3] += b2f_lo(pa.w); ahi[3] += b2f_hi(pa.w);
          alo[4] += b2f_lo(pb.x); ahi[4] += b2f_hi(pb.x);
          alo[5] += b2f_lo(pb.y); ahi[5] += b2f_hi(pb.y);
          alo[6] += b2f_lo(pb.z); ahi[6] += b2f_hi(pb.z);
          alo[7] += b2f_lo(pb.w); ahi[7] += b2f_hi(pb.w);
        }
      }
      // rare spill fallback: whole wave scans per offending node
      u64 over = __ballot(c == 0 && cnt > CAP);
      if (over) {
        int sc = *spillcnt;
        while (over) {
          int bit = __ffsll((long long)over) - 1;
          over &= over - 1;
          int gsel = bit >> 2;
          int n_t = __shfl(n, bit);
          int halfo_t = __shfl(halfo, bit);
          for (int bb = 0; bb < sc; bb += 64) {
            int i = bb + lane;
            u64 ent = (i < sc) ? spill[i] : 0xffffffffffffffffull;
            bool m = ((int)(ent >> 32) == n_t);
            u64 bal = __ballot(m);
            int slo = (int)(ent & 0xffffffffu);
            while (bal) {
              int l = __ffsll((long long)bal) - 1;
              bal &= bal - 1;
              int s = __shfl(slo, l);
              if (g4 == gsel) {
                const u32* rowp = yrow + (size_t)s * 64 + halfo_t + c * 8;
                uint4 pa = *(const uint4*)rowp;
                uint4 pb = *(const uint4*)(rowp + 4);
                alo[0] += b2f_lo(pa.x); ahi[0] += b2f_hi(pa.x);
                alo[1] += b2f_lo(pa.y); ahi[1] += b2f_hi(pa.y);
                alo[2] += b2f_lo(pa.z); ahi[2] += b2f_hi(pa.z);
                alo[3] += b2f_lo(pa.w); ahi[3] += b2f_hi(pa.w);
                alo[4] += b2f_lo(pb.x); ahi[4] += b2f_hi(pb.x);
                alo[5] += b2f_lo(pb.y); ahi[5] += b2f_hi(pb.y);
                alo[6] += b2f_lo(pb.z); ahi[6] += b2f_hi(pb.z);
                alo[7] += b2f_lo(pb.w); ahi[7] += b2f_hi(pb.w);
              }
            }
          }
        }
      }
      // finalize -> zl (layout identical to R6's z1a packing)
      float psum = pspill + myb;
      float inv = 1.f / (float)(cnt > 1 ? cnt : 1);
      float pm = mod ? psum * inv : 0.f;
      const u32* f1p = ((const u32*)f1) + (size_t)n * 32 + c * 8;
      uint4 fa = *(const uint4*)f1p;
      uint4 fb = *(const uint4*)(f1p + 4);
      const float4* wp4 = (const float4*)w_pos;
      float4 wpa = wp4[c * 4 + 0], wpb = wp4[c * 4 + 1];
      float4 wpc = wp4[c * 4 + 2], wpd = wp4[c * 4 + 3];
      u32 zr[8];
#pragma unroll
      for (int m = 0; m < 8; m++) {
        u32 fw = (m == 0) ? fa.x : (m == 1) ? fa.y : (m == 2) ? fa.z : (m == 3) ? fa.w
               : (m == 4) ? fb.x : (m == 5) ? fb.y : (m == 6) ? fb.z : fb.w;
        float z0 = alo[m] * inv + b2f_lo(fw);
        float z1v = ahi[m] * inv + b2f_hi(fw);
        if (mod) {
          float4 w4 = ((m >> 1) == 0) ? wpa : ((m >> 1) == 1) ? wpb
                    : ((m >> 1) == 2) ? wpc : wpd;
          float wx = (m & 1) ? w4.z : w4.x;
          float wy = (m & 1) ? w4.w : w4.y;
          z0 += pm * wx;
          z1v += pm * wy;
        }
        zr[m] = (u32)f2b(leaky(z0)) | ((u32)f2b(leaky(z1v)) << 16);
      }
      u32* zp = &zl[wv][g4][c * 8];
      *(uint4*)zp = make_uint4(zr[0], zr[1], zr[2], zr[3]);
      *(uint4*)(zp + 4) = make_uint4(zr[4], zr[5], zr[6], zr[7]);
    }

    // ===== tail phase 1: layer-2 both types, select, relu -> tbuf ==========
    int id = batch * 16 + lid;
    if (id >= N) id = N - 1;
    const u16* zrow = (const u16*)zl[wv][lid];  // 72 u16 per row (36 dwords)
    bf16x8 a0 = *(const bf16x8*)&zrow[q * 8];
    bf16x8 a1 = *(const bf16x8*)&zrow[32 + q * 8];
    bool mod_[4], kp_[4];
#pragma unroll
    for (int r = 0; r < 4; r++) {
      int ii = batch * 16 + q * 4 + r;
      if (ii >= N) ii = N - 1;
      mod_[r] = (mbits[ii >> 5] >> (ii & 31)) & 1;
      kp_[r] = (is_po[ii] != 1);
    }
#pragma unroll
    for (int nt = 0; nt < 8; nt++) {
      f32x4 cm = {0.f, 0.f, 0.f, 0.f}, cg = {0.f, 0.f, 0.f, 0.f};
      cm = mfma16(a0, *(const bf16x8*)&w2[0][(nt * 16 + lid) * P64 + q * 8], cm);
      cm = mfma16(a1, *(const bf16x8*)&w2[0][(nt * 16 + lid) * P64 + 32 + q * 8], cm);
      cg = mfma16(a0, *(const bf16x8*)&w2[1][(nt * 16 + lid) * P64 + q * 8], cg);
      cg = mfma16(a1, *(const bf16x8*)&w2[1][(nt * 16 + lid) * P64 + 32 + q * 8], cg);
#pragma unroll
      for (int r = 0; r < 4; r++) {
        float v = mod_[r] ? cm[r] + b2m[nt] : cg[r] + b2g[nt];
        if (kp_[r]) v = fmaxf(v, 0.f);
        tbuf[wv][(q * 4 + r) * P128 + nt * 16 + lid] = f2b(v);
      }
    }

    // ===== tail phase 2: readout (h A-frags from tbuf + global branch) =====
    bf16x8 ah[4];
#pragma unroll
    for (int kt = 0; kt < 4; kt++)
      ah[kt] = *(const bf16x8*)&tbuf[wv][lid * P128 + kt * 32 + q * 8];
    float lv = level[id];
    bf16x8 ag[2];
#pragma unroll
    for (int kt = 0; kt < 2; kt++)
#pragma unroll
      for (int j = 0; j < 8; j++)
        ag[kt][j] = (__bf16)leaky(lv * gw[kt][j] + gb[kt][j]);

    f32x4 accv[8];
#pragma unroll
    for (int nt = 0; nt < 8; nt++) {
      f32x4 cc = {0.f, 0.f, 0.f, 0.f};
#pragma unroll
      for (int kt = 0; kt < 4; kt++)
        cc = mfma16(ah[kt], *(const bf16x8*)&wt_oh[(nt * 16 + lid) * P128 + kt * 32 + q * 8], cc);
#pragma unroll
      for (int kt = 0; kt < 2; kt++)
        cc = mfma16(ag[kt], *(const bf16x8*)&gt[(nt * 16 + lid) * P64 + kt * 32 + q * 8], cc);
      accv[nt] = cc;
    }
    float p[4];
#pragma unroll
    for (int r = 0; r < 4; r++) {
      float s = 0.f;
#pragma unroll
      for (int nt = 0; nt < 8; nt++) s += leaky(accv[nt][r] + bpv[nt]) * w2o[nt];
      p[r] = s;
    }
#pragma unroll
    for (int r = 0; r < 4; r++)
#pragma unroll
      for (int off = 1; off < 16; off <<= 1) p[r] += __shfl_xor(p[r], off, 16);
    if (lid == 0) {
#pragma unroll
      for (int r = 0; r < 4; r++) {
        int idr = batch * 16 + q * 4 + r;
        if (idr >= N) idr = N - 1;
        out[idr] = p[r] + ob2;
      }
    }
  }
}

extern "C" void kernel_launch(void* const* d_in, const int* in_sizes, int n_in,
                              void* d_out, int out_size, void* d_ws, size_t ws_size,
                              hipStream_t stream) {
  const float* feat = (const float*)d_in[0];
  const float* pi_feat = (const float*)d_in[1];
  const float* level = (const float*)d_in[2];
  const float* bitpos = (const float*)d_in[3];
  const int* is_po = (const int*)d_in[4];
  const int* is_module = (const int*)d_in[5];
  const int* src_m = (const int*)d_in[6];
  const int* dst_m = (const int*)d_in[7];
  const int* src_g = (const int*)d_in[8];
  const int* dst_g = (const int*)d_in[9];
  const float* pi_w1 = (const float*)d_in[10];
  const float* pi_b1 = (const float*)d_in[11];
  const float* pi_w2 = (const float*)d_in[12];
  const float* pi_b2 = (const float*)d_in[13];
  const float* nm_w1 = (const float*)d_in[14];
  const float* nm_b1 = (const float*)d_in[15];
  const float* nm_w2 = (const float*)d_in[16];
  const float* nm_b2 = (const float*)d_in[17];
  const float* ng_w1 = (const float*)d_in[18];
  const float* ng_b1 = (const float*)d_in[19];
  const float* ng_w2 = (const float*)d_in[20];
  const float* ng_b2 = (const float*)d_in[21];
  const float* g_w1 = (const float*)d_in[22];
  const float* g_b1 = (const float*)d_in[23];
  const float* g_w2 = (const float*)d_in[24];
  const float* g_b2 = (const float*)d_in[25];
  const float* o_w1 = (const float*)d_in[26];
  const float* o_b1 = (const float*)d_in[27];
  const float* o_w2 = (const float*)d_in[28];
  const float* o_b2 = (const float*)d_in[29];

  int N = in_sizes[0] / 64;
  int E = in_sizes[3];

  char* ws = (char*)d_ws;
  size_t off = 0;
  auto alloc = [&](size_t bytes) {
    char* p = ws + off;
    off += (bytes + 255) & ~(size_t)255;
    return p;
  };
  int* rec = (int*)alloc(((size_t)N * RSTRIDE + 64) * 4);
  int* spillcnt = (int*)alloc(16);
  u64* spill = (u64*)alloc((size_t)2 * E * 8);
  u32* mbits = (u32*)alloc((size_t)((N + 31) / 32) * 4);
  u16* y0 = (u16*)alloc((size_t)N * 128 * 2);
  u16* f1 = (u16*)alloc((size_t)N * 64 * 2);
  u16* wt_yc = (u16*)alloc(9216 * 2);
  float* bias_y = (float*)alloc(128 * 4);
  u16* wt_f1m = (u16*)alloc(4608 * 2);
  u16* wt_f1g = (u16*)alloc(4608 * 2);
  float* w_pos = (float*)alloc(64 * 4);
  u16* wt2m = (u16*)alloc(9216 * 2);
  u16* wt2g = (u16*)alloc(9216 * 2);
  u16* wt_oh = (u16*)alloc(17408 * 2);
  u16* gt = (u16*)alloc(9216 * 2);
  float* bp = (float*)alloc(128 * 4);

  // 0. init: pre-weight folds (once) + mbits ballot + record zero + spillcnt
  int init_items = 18560 + ((N + 63) & ~63);
  k_init<<<(init_items + 255) / 256, 256, 0, stream>>>(
      nm_w1, ng_w1, pi_w2, pi_b2, is_module,
      wt_yc, bias_y, wt_f1m, wt_f1g, rec, spillcnt, mbits, N);

  // 1. fused: tail-weight prep || edge scatter || node precompute
  k_mid<<<PREPB + SBLK + PBLK, 512, 0, stream>>>(
      src_m, dst_m, src_g, dst_g, mbits, bitpos, rec, spill, spillcnt, E,
      pi_feat, feat, pi_w1, pi_b1, wt_yc, bias_y, wt_f1m, wt_f1g,
      nm_b1, ng_b1, y0, f1,
      nm_w1, nm_w2, ng_w2, o_w1, o_b1, g_w2, g_b2,
      wt2m, wt2g, wt_oh, gt, bp, w_pos, N);

  // 2. fused gather+tail: 16-node-parallel gather -> LDS z -> layer2+readout
  k_gt2<<<256, 512, 0, stream>>>(
      y0, rec, spill, spillcnt, mbits, f1, w_pos,
      wt2m, wt2g, nm_b2, ng_b2, is_po, level, g_w1, g_b1,
      wt_oh, gt, bp, o_w2, o_b2, (float*)d_out, N);
}